// Round 2
// baseline (11383.771 us; speedup 1.0000x reference)
//
#include <hip/hip_runtime.h>
#include <math.h>

#define BB 256
#define SS 512
#define II 128
#define HH 256

typedef unsigned short ushort_t;
typedef unsigned int uint32;

// d_ws bf16 weight-blob element offsets (each 16B-aligned: multiples of 8)
#define OFF_WA   0          // 128*384 = 49152
#define OFF_BA   49152      // 128
#define OFF_WIH  49280      // 768*128 = 98304
#define OFF_BIH  147584     // 768
#define OFF_WHH  148352     // 768*256 = 196608
#define OFF_BHH  344960     // 768
#define OFF_WT   345728     // 256
#define OFF_BT   345984     // 1 (pad to 8)
#define OFF_WF   345992     // 256
#define OFF_BF   346248     // 1
#define WS_ELEMS 346256     // ~692 KB of bf16 in d_ws

__device__ __forceinline__ float b2f(ushort_t u) {
    union { uint32 i; float f; } v; v.i = ((uint32)u) << 16; return v.f;
}
__device__ __forceinline__ float lo2f(uint32 w) {
    union { uint32 i; float f; } v; v.i = w << 16; return v.f;
}
__device__ __forceinline__ float hi2f(uint32 w) {
    union { uint32 i; float f; } v; v.i = w & 0xFFFF0000u; return v.f;
}
__device__ __forceinline__ ushort_t f2b(float f) {
    union { float f; uint32 i; } v; v.f = f;
    uint32 r = (v.i + 0x7FFFu + ((v.i >> 16) & 1u)) >> 16;
    return (ushort_t)r;
}

struct F8 { float4 a, b; };
__device__ __forceinline__ F8 ld8(const float* p) {
    F8 r;
    r.a = *(const float4*)p;
    r.b = *(const float4*)(p + 4);
    return r;
}
__device__ __forceinline__ float fma8(uint4 w, const F8& v, float acc) {
    acc = fmaf(lo2f(w.x), v.a.x, acc); acc = fmaf(hi2f(w.x), v.a.y, acc);
    acc = fmaf(lo2f(w.y), v.a.z, acc); acc = fmaf(hi2f(w.y), v.a.w, acc);
    acc = fmaf(lo2f(w.z), v.b.x, acc); acc = fmaf(hi2f(w.z), v.b.y, acc);
    acc = fmaf(lo2f(w.w), v.b.z, acc); acc = fmaf(hi2f(w.w), v.b.w, acc);
    return acc;
}

// fp32 -> bf16 converter (weights into d_ws blob)
__global__ void cvt_f32_bf16(const float* __restrict__ src, ushort_t* __restrict__ dst, int n) {
    int i = blockIdx.x * 256 + threadIdx.x;
    if (i < n) dst[i] = f2b(src[i]);
}

// One block per batch row. 256 threads. Sequential over S=512 steps.
// Weights (bf16, from d_ws) are streamed from L2 each step; state
// (h, online-softmax context) lives in LDS.
__global__ __launch_bounds__(256) void da_rnn_kernel(
    const float* __restrict__ x,          // fp32 input [B,S,I]
    const ushort_t* __restrict__ wsb,     // bf16 weight blob in d_ws
    float* __restrict__ out)              // fp32 output [B,1]
{
    const int b    = blockIdx.x;
    const int tid  = threadIdx.x;
    const int lane = tid & 63;
    const int wv   = tid >> 6;

    __shared__ __align__(16) float sh[HH];      // hidden state (fp32)
    __shared__ __align__(16) float sx[II];      // x_t (fp32)
    __shared__ __align__(16) float sxw[II];     // alpha * x_t
    __shared__ __align__(16) float sscore[II];
    __shared__ __align__(16) float sred[256];
    __shared__ __align__(16) float sc[HH];      // online context accumulator
    __shared__ float sbc[8];  // [0]=max [1]=sum [2]=a [3]=w [4]=m_run [5]=l_run
    __shared__ float swave[4];

    sh[tid] = 0.f;
    sc[tid] = 0.f;
    // scores are tanh in [-1,1]; -2 is a safe finite "minus infinity" since
    // l_run = c = 0 makes the first-step rescale factor irrelevant.
    if (tid == 0) { sbc[4] = -2.0f; sbc[5] = 0.f; }

    // per-thread persistent parameters (bf16 blob)
    const int j = tid;                    // hidden index 0..255
    const float bihr = b2f(wsb[OFF_BIH + j]);
    const float bihz = b2f(wsb[OFF_BIH + j + HH]);
    const float bihn = b2f(wsb[OFF_BIH + j + 2*HH]);
    const float bhhr = b2f(wsb[OFF_BHH + j]);
    const float bhhz = b2f(wsb[OFF_BHH + j + HH]);
    const float bhhn = b2f(wsb[OFF_BHH + j + 2*HH]);
    const float wt_j = b2f(wsb[OFF_WT + j]);
    const float wf_j = b2f(wsb[OFF_WF + j]);

    const int sj   = tid & 127;           // score index 0..127
    const int half = tid >> 7;            // split-k half for W_a
    const float ba_j = b2f(wsb[OFF_BA + sj]);

    const float* xrow = x + (size_t)b * SS * II;
    const ushort_t* warow = wsb + OFF_WA + (size_t)sj * (II + HH);
    const ushort_t* wih_r = wsb + OFF_WIH + (size_t)j * II;
    const ushort_t* wih_z = wsb + OFF_WIH + (size_t)(j + HH) * II;
    const ushort_t* wih_n = wsb + OFF_WIH + (size_t)(j + 2*HH) * II;
    const ushort_t* whh_r = wsb + OFF_WHH + (size_t)j * HH;
    const ushort_t* whh_z = wsb + OFF_WHH + (size_t)(j + HH) * HH;
    const ushort_t* whh_n = wsb + OFF_WHH + (size_t)(j + 2*HH) * HH;

    __syncthreads();

    for (int t = 0; t < SS; ++t) {
        // ---- load x_t (fp32 -> LDS) ----
        if (tid < II) sx[tid] = xrow[t * II + tid];
        __syncthreads();

        // ---- input attention scores: scores[sj] = tanh(Wa[sj,:] . [x_t; h] + ba) ----
        // half 0 covers k in [0,192) (x 0..127, h 0..63), half 1 covers k in [192,384)
        float acc = 0.f;
        if (half == 0) {
            for (int k = 0; k < 128; k += 8) {
                uint4 w8 = *(const uint4*)(warow + k);
                acc = fma8(w8, ld8(sx + k), acc);
            }
            for (int k = 128; k < 192; k += 8) {
                uint4 w8 = *(const uint4*)(warow + k);
                acc = fma8(w8, ld8(sh + (k - 128)), acc);
            }
        } else {
            for (int k = 192; k < 384; k += 8) {
                uint4 w8 = *(const uint4*)(warow + k);
                acc = fma8(w8, ld8(sh + (k - 128)), acc);
            }
        }
        sred[tid] = acc;
        __syncthreads();

        if (tid < II) {
            float s = sred[tid] + sred[tid + 128] + ba_j;
            sscore[tid] = tanhf(s);
        }
        __syncthreads();

        // ---- softmax over 128 scores ----
        if (tid < 64) {
            float m = fmaxf(sscore[tid], sscore[tid + 64]);
            for (int off = 32; off; off >>= 1) m = fmaxf(m, __shfl_down(m, off));
            if (tid == 0) sbc[0] = m;
        }
        __syncthreads();
        if (tid < II) sscore[tid] = expf(sscore[tid] - sbc[0]);
        __syncthreads();
        if (tid < 64) {
            float sm = sscore[tid] + sscore[tid + 64];
            for (int off = 32; off; off >>= 1) sm += __shfl_down(sm, off);
            if (tid == 0) sbc[1] = sm;
        }
        __syncthreads();
        if (tid < II) sxw[tid] = sscore[tid] / sbc[1] * sx[tid];
        __syncthreads();

        // ---- GRU gates: gi = Wih . xw + bih ; gh = Whh . h + bhh ----
        float gir = bihr, giz = bihz, gin = bihn;
        for (int k = 0; k < II; k += 8) {
            F8 v = ld8(sxw + k);
            uint4 a0 = *(const uint4*)(wih_r + k);
            uint4 a1 = *(const uint4*)(wih_z + k);
            uint4 a2 = *(const uint4*)(wih_n + k);
            gir = fma8(a0, v, gir);
            giz = fma8(a1, v, giz);
            gin = fma8(a2, v, gin);
        }
        float ghr = bhhr, ghz = bhhz, ghn = bhhn;
        for (int k = 0; k < HH; k += 8) {
            F8 v = ld8(sh + k);
            uint4 a0 = *(const uint4*)(whh_r + k);
            uint4 a1 = *(const uint4*)(whh_z + k);
            uint4 a2 = *(const uint4*)(whh_n + k);
            ghr = fma8(a0, v, ghr);
            ghz = fma8(a1, v, ghz);
            ghn = fma8(a2, v, ghn);
        }

        const float h_old = sh[j];
        const float r = 1.f / (1.f + expf(-(gir + ghr)));
        const float z = 1.f / (1.f + expf(-(giz + ghz)));
        const float n = tanhf(gin + r * ghn);
        const float h_new = (1.f - z) * n + z * h_old;

        __syncthreads();          // everyone finished reading old h
        sh[j] = h_new;

        // ---- online temporal attention: s_t = tanh(Wt . h_new + bt) ----
        float p = wt_j * h_new;
        for (int off = 32; off; off >>= 1) p += __shfl_down(p, off);
        if (lane == 0) swave[wv] = p;
        __syncthreads();
        if (tid == 0) {
            float dot = swave[0] + swave[1] + swave[2] + swave[3] + b2f(wsb[OFF_BT]);
            float s = tanhf(dot);
            float m_old = sbc[4], l_old = sbc[5];
            float m_new = fmaxf(m_old, s);
            float a = expf(m_old - m_new);   // multiplies l=c=0 on first step
            float w = expf(s - m_new);
            sbc[4] = m_new;
            sbc[5] = l_old * a + w;
            sbc[2] = a;
            sbc[3] = w;
        }
        __syncthreads();
        sc[j] = sc[j] * sbc[2] + sbc[3] * h_new;
    }

    // ---- epilogue: context = c / l ; out = sigmoid(Wf . context + bf) ----
    __syncthreads();
    float ctx = sc[j] / sbc[5];
    float p = wf_j * ctx;
    for (int off = 32; off; off >>= 1) p += __shfl_down(p, off);
    if (lane == 0) swave[wv] = p;
    __syncthreads();
    if (tid == 0) {
        float logit = swave[0] + swave[1] + swave[2] + swave[3] + b2f(wsb[OFF_BF]);
        float o = 1.f / (1.f + expf(-logit));
        out[b] = o;
    }
}

extern "C" void kernel_launch(void* const* d_in, const int* in_sizes, int n_in,
                              void* d_out, int out_size, void* d_ws, size_t ws_size,
                              hipStream_t stream) {
    ushort_t* wsb = (ushort_t*)d_ws;

    // convert all fp32 weights to bf16 into the d_ws blob (every call; ws is re-poisoned)
    struct { int src_idx; int off; int n; } cv[10] = {
        {1, OFF_WA,  II * (II + HH)},   // W_a  [128,384]
        {2, OFF_BA,  II},               // b_a
        {3, OFF_WIH, 3 * HH * II},      // W_ih [768,128]
        {4, OFF_BIH, 3 * HH},           // b_ih
        {5, OFF_WHH, 3 * HH * HH},      // W_hh [768,256]
        {6, OFF_BHH, 3 * HH},           // b_hh
        {7, OFF_WT,  HH},               // W_t  [1,256]
        {8, OFF_BT,  1},                // b_t
        {9, OFF_WF,  HH},               // W_f  [1,256]
        {10, OFF_BF, 1},                // b_f
    };
    for (int i = 0; i < 10; ++i) {
        int blocks = (cv[i].n + 255) / 256;
        cvt_f32_bf16<<<dim3(blocks), dim3(256), 0, stream>>>(
            (const float*)d_in[cv[i].src_idx], wsb + cv[i].off, cv[i].n);
    }

    da_rnn_kernel<<<dim3(BB), dim3(256), 0, stream>>>(
        (const float*)d_in[0], wsb, (float*)d_out);
}

// Round 3
// 4708.554 us; speedup vs baseline: 2.4177x; 2.4177x over previous
//
#include <hip/hip_runtime.h>
#include <math.h>

#define BB 256
#define SS 512
#define II 128
#define HH 256

typedef unsigned short ushort_t;
typedef unsigned int uint32;

// d_ws bf16 blob element offsets (each a multiple of 8 -> 16B aligned)
#define OFF_WA   0          // 128*384 = 49152   (swizzled)
#define OFF_BA   49152      // 128
#define OFF_WIH  49280      // 768*128 = 98304   (swizzled)
#define OFF_BIH  147584     // 768
#define OFF_WHH  148352     // 768*256 = 196608  (swizzled)
#define OFF_BHH  344960     // 768
#define OFF_WT   345728     // 256
#define OFF_BT   345984     // 1 (padded to 8)
#define OFF_WF   345992     // 256
#define OFF_BF   346248     // 1

__device__ __forceinline__ float b2f(ushort_t u) {
    union { uint32 i; float f; } v; v.i = ((uint32)u) << 16; return v.f;
}
__device__ __forceinline__ float lo2f(uint32 w) {
    union { uint32 i; float f; } v; v.i = w << 16; return v.f;
}
__device__ __forceinline__ float hi2f(uint32 w) {
    union { uint32 i; float f; } v; v.i = w & 0xFFFF0000u; return v.f;
}
__device__ __forceinline__ ushort_t f2b(float f) {
    union { float f; uint32 i; } v; v.f = f;
    uint32 r = (v.i + 0x7FFFu + ((v.i >> 16) & 1u)) >> 16;
    return (ushort_t)r;
}

struct F8 { float4 a, b; };
__device__ __forceinline__ F8 ld8(const float* p) {
    F8 r;
    r.a = *(const float4*)p;
    r.b = *(const float4*)(p + 4);
    return r;
}
__device__ __forceinline__ float fma8(uint4 w, const F8& v, float acc) {
    acc = fmaf(lo2f(w.x), v.a.x, acc); acc = fmaf(hi2f(w.x), v.a.y, acc);
    acc = fmaf(lo2f(w.y), v.a.z, acc); acc = fmaf(hi2f(w.y), v.a.w, acc);
    acc = fmaf(lo2f(w.z), v.b.x, acc); acc = fmaf(hi2f(w.z), v.b.y, acc);
    acc = fmaf(lo2f(w.w), v.b.z, acc); acc = fmaf(hi2f(w.w), v.b.w, acc);
    return acc;
}

// Linear fp32 -> bf16 (biases, small vectors)
__global__ void cvt_f32_bf16(const float* __restrict__ src, ushort_t* __restrict__ dst, int n) {
    int i = blockIdx.x * 256 + threadIdx.x;
    if (i < n) dst[i] = f2b(src[i]);
}

// Swizzled fp32 -> bf16 for weight matrices [rows, chunks*8]:
// uint4 index = ((row/64)*chunks + c)*64 + (row%64)
// so that in the main kernel a wave (64 consecutive rows) reading chunk c
// issues one fully-coalesced 1KB load.
__global__ void cvt_swz(const float* __restrict__ src, ushort_t* __restrict__ dst,
                        int rows, int chunks) {
    int t = blockIdx.x * 256 + threadIdx.x;
    if (t >= rows * chunks) return;
    int row = t / chunks, c = t % chunks;
    const float* s = src + (size_t)row * chunks * 8 + c * 8;
    uint32 p0 = (uint32)f2b(s[0]) | ((uint32)f2b(s[1]) << 16);
    uint32 p1 = (uint32)f2b(s[2]) | ((uint32)f2b(s[3]) << 16);
    uint32 p2 = (uint32)f2b(s[4]) | ((uint32)f2b(s[5]) << 16);
    uint32 p3 = (uint32)f2b(s[6]) | ((uint32)f2b(s[7]) << 16);
    uint4 v; v.x = p0; v.y = p1; v.z = p2; v.w = p3;
    ((uint4*)dst)[((size_t)(row >> 6) * chunks + c) * 64 + (row & 63)] = v;
}

// One block (1024 threads, 16 waves) per batch row; sequential over S=512.
// Weights stream coalesced from L2; state lives in LDS.
__global__ __launch_bounds__(1024, 4) void da_rnn_kernel(
    const float* __restrict__ x,          // fp32 [B,S,I]
    const ushort_t* __restrict__ wsb,     // bf16 blob in d_ws
    float* __restrict__ out)              // fp32 [B,1]
{
    const int b    = blockIdx.x;
    const int tid  = threadIdx.x;
    const int lane = tid & 63;
    const int wv   = tid >> 6;

    __shared__ __align__(16) float sh[HH];       // hidden state
    __shared__ __align__(16) float sx[2][II];    // x_t double buffer
    __shared__ __align__(16) float sxw[II];      // alpha * x_t
    __shared__ __align__(16) float sred[1024];   // Wa split-k partials
    __shared__ __align__(16) float sgi[3*HH];    // gi (bias included)
    __shared__ __align__(16) float sgh[3*HH];    // gh (bias included)
    __shared__ __align__(16) float sc[HH];       // online context accumulator
    __shared__ float sbc[8];   // [2]=a [3]=w [4]=m_run [5]=l_run
    __shared__ float swave[4];

    if (tid < HH) { sh[tid] = 0.f; sc[tid] = 0.f; }
    // tanh scores are >= -1; -2 is a safe finite "minus infinity" since
    // l_run = c = 0 makes the first-step rescale factor irrelevant.
    if (tid == 0) { sbc[4] = -2.0f; sbc[5] = 0.f; }

    // ---- persistent per-thread parameters ----
    // Wa phase: row = tid&127, kslice s = tid>>7 (uniform within a wave)
    const int row = tid & 127;
    const int s   = tid >> 7;
    const uint4* wa_base = (const uint4*)(wsb + OFF_WA)
                         + (size_t)(row >> 6) * 48 * 64 + (row & 63);

    // gate phase: thread j = tid < 768 owns full gate row j
    const uint4* wih_base = (const uint4*)(wsb + OFF_WIH)
                          + (size_t)(tid >> 6) * 16 * 64 + lane;
    const uint4* whh_base = (const uint4*)(wsb + OFF_WHH)
                          + (size_t)(tid >> 6) * 32 * 64 + lane;
    float bias_i = 0.f, bias_h = 0.f;
    if (tid < 3 * HH) { bias_i = b2f(wsb[OFF_BIH + tid]); bias_h = b2f(wsb[OFF_BHH + tid]); }

    // softmax wave (wave 0) biases
    float ba_a = 0.f, ba_b = 0.f;
    if (wv == 0) { ba_a = b2f(wsb[OFF_BA + lane]); ba_b = b2f(wsb[OFF_BA + 64 + lane]); }

    // h-update threads
    float wt_j = 0.f, wf_j = 0.f;
    if (tid < HH) { wt_j = b2f(wsb[OFF_WT + tid]); wf_j = b2f(wsb[OFF_WF + tid]); }

    const float* xrow = x + (size_t)b * SS * II;

    // prologue: load x_0
    if (tid < II) sx[0][tid] = xrow[tid];
    __syncthreads();

    for (int t = 0; t < SS; ++t) {
        const int p = t & 1;

        // ---- Wa partials: thread (row, s) covers k in [48s, 48s+48) ----
        float acc = 0.f;
        #pragma unroll
        for (int i = 0; i < 6; ++i) {
            const int c = s * 6 + i;            // chunk (wave-uniform)
            const int k = c * 8;
            const float* src = (k < 128) ? &sx[p][k] : &sh[k - 128];
            acc = fma8(wa_base[c * 64], ld8(src), acc);
        }
        sred[tid] = acc;
        __syncthreads();                                         // B_a

        // ---- scores + softmax + xw, entirely inside wave 0 ----
        if (wv == 0) {
            float s_a = ba_a, s_b = ba_b;
            #pragma unroll
            for (int q = 0; q < 8; ++q) {
                s_a += sred[lane + 128 * q];
                s_b += sred[lane + 64 + 128 * q];
            }
            s_a = tanhf(s_a); s_b = tanhf(s_b);
            float m = fmaxf(s_a, s_b);
            for (int off = 32; off; off >>= 1) m = fmaxf(m, __shfl_xor(m, off));
            float e_a = expf(s_a - m), e_b = expf(s_b - m);
            float sum = e_a + e_b;
            for (int off = 32; off; off >>= 1) sum += __shfl_xor(sum, off);
            float inv = 1.f / sum;
            sxw[lane]      = e_a * inv * sx[p][lane];
            sxw[lane + 64] = e_b * inv * sx[p][lane + 64];
        }
        __syncthreads();                                         // B_b

        // ---- gates: thread j < 768 computes gi[j], gh[j] (full K) ----
        if (tid < 3 * HH) {
            float gi = bias_i;
            #pragma unroll 8
            for (int c = 0; c < 16; ++c)
                gi = fma8(wih_base[c * 64], ld8(sxw + c * 8), gi);
            float gh = bias_h;
            #pragma unroll 8
            for (int c = 0; c < 32; ++c)
                gh = fma8(whh_base[c * 64], ld8(sh + c * 8), gh);
            sgi[tid] = gi;
            sgh[tid] = gh;
        } else if (tid < 3 * HH + II) {
            // waves 12-13: prefetch x_{t+1}
            if (t + 1 < SS) sx[p ^ 1][tid - 3 * HH] = xrow[(t + 1) * II + (tid - 3 * HH)];
        }
        __syncthreads();                                         // B_c

        // ---- h update + temporal attention score (threads 0..255) ----
        float h_new = 0.f;
        if (tid < HH) {
            const float r = 1.f / (1.f + expf(-(sgi[tid] + sgh[tid])));
            const float z = 1.f / (1.f + expf(-(sgi[tid + HH] + sgh[tid + HH])));
            const float n = tanhf(sgi[tid + 2 * HH] + r * sgh[tid + 2 * HH]);
            h_new = (1.f - z) * n + z * sh[tid];
            sh[tid] = h_new;
            float pdot = wt_j * h_new;
            for (int off = 32; off; off >>= 1) pdot += __shfl_down(pdot, off);
            if (lane == 0) swave[wv] = pdot;
        }
        __syncthreads();                                         // B_d
        if (tid == 0) {
            float dot = swave[0] + swave[1] + swave[2] + swave[3] + b2f(wsb[OFF_BT]);
            float st = tanhf(dot);
            float m_old = sbc[4], l_old = sbc[5];
            float m_new = fmaxf(m_old, st);
            float a = expf(m_old - m_new);
            float w = expf(st - m_new);
            sbc[4] = m_new;
            sbc[5] = l_old * a + w;
            sbc[2] = a;
            sbc[3] = w;
        }
        __syncthreads();                                         // B_e
        if (tid < HH) sc[tid] = sc[tid] * sbc[2] + sbc[3] * h_new;
    }

    // ---- epilogue: context = c/l ; out = sigmoid(Wf . ctx + bf) ----
    if (tid < HH) {
        float ctx = sc[tid] / sbc[5];
        float pdot = wf_j * ctx;
        for (int off = 32; off; off >>= 1) pdot += __shfl_down(pdot, off);
        if (lane == 0) swave[wv] = pdot;
    }
    __syncthreads();
    if (tid == 0) {
        float logit = swave[0] + swave[1] + swave[2] + swave[3] + b2f(wsb[OFF_BF]);
        out[b] = 1.f / (1.f + expf(-logit));
    }
}

extern "C" void kernel_launch(void* const* d_in, const int* in_sizes, int n_in,
                              void* d_out, int out_size, void* d_ws, size_t ws_size,
                              hipStream_t stream) {
    ushort_t* wsb = (ushort_t*)d_ws;

    // swizzled weight conversions (every call; d_ws is re-poisoned)
    cvt_swz<<<dim3((128 * 48 + 255) / 256), dim3(256), 0, stream>>>(
        (const float*)d_in[1], wsb + OFF_WA, 128, 48);           // W_a  [128,384]
    cvt_swz<<<dim3((768 * 16 + 255) / 256), dim3(256), 0, stream>>>(
        (const float*)d_in[3], wsb + OFF_WIH, 768, 16);          // W_ih [768,128]
    cvt_swz<<<dim3((768 * 32 + 255) / 256), dim3(256), 0, stream>>>(
        (const float*)d_in[5], wsb + OFF_WHH, 768, 32);          // W_hh [768,256]

    struct { int src_idx; int off; int n; } cv[7] = {
        {2, OFF_BA,  II},        // b_a
        {4, OFF_BIH, 3 * HH},    // b_ih
        {6, OFF_BHH, 3 * HH},    // b_hh
        {7, OFF_WT,  HH},        // W_t
        {8, OFF_BT,  1},         // b_t
        {9, OFF_WF,  HH},        // W_f
        {10, OFF_BF, 1},         // b_f
    };
    for (int i = 0; i < 7; ++i) {
        int blocks = (cv[i].n + 255) / 256;
        cvt_f32_bf16<<<dim3(blocks), dim3(256), 0, stream>>>(
            (const float*)d_in[cv[i].src_idx], wsb + cv[i].off, cv[i].n);
    }

    da_rnn_kernel<<<dim3(BB), dim3(1024), 0, stream>>>(
        (const float*)d_in[0], wsb, (float*)d_out);
}

// Round 4
// 2674.864 us; speedup vs baseline: 4.2558x; 1.7603x over previous
//
#include <hip/hip_runtime.h>
#include <math.h>

#define BB 256
#define SS 512
#define II 128
#define HH 256

typedef unsigned short ushort_t;
typedef unsigned int uint32;

// d_ws bf16 blob element offsets (each a multiple of 8 -> 16B aligned)
#define OFF_WA   0          // 128*384 = 49152   (swizzled, 48 chunks)
#define OFF_BA   49152      // 128
#define OFF_WIH  49280      // 768*128 = 98304   (swizzled, 16 chunks)
#define OFF_BIH  147584     // 768
#define OFF_WHH  148352     // 768*256 = 196608  (swizzled, 32 chunks)
#define OFF_BHH  344960     // 768
#define OFF_WT   345728     // 256
#define OFF_BT   345984     // 1 (padded to 8)
#define OFF_WF   345992     // 256
#define OFF_BF   346248     // 1

__device__ __forceinline__ float b2f(ushort_t u) {
    union { uint32 i; float f; } v; v.i = ((uint32)u) << 16; return v.f;
}
__device__ __forceinline__ float lo2f(uint32 w) {
    union { uint32 i; float f; } v; v.i = w << 16; return v.f;
}
__device__ __forceinline__ float hi2f(uint32 w) {
    union { uint32 i; float f; } v; v.i = w & 0xFFFF0000u; return v.f;
}
__device__ __forceinline__ ushort_t f2b(float f) {
    union { float f; uint32 i; } v; v.f = f;
    uint32 r = (v.i + 0x7FFFu + ((v.i >> 16) & 1u)) >> 16;
    return (ushort_t)r;
}
__device__ __forceinline__ uint32 pack2(float a, float b) {
    return (uint32)f2b(a) | ((uint32)f2b(b) << 16);
}

// packed-bf16 dual-MAC: v_dot2_f32_bf16 if available, unpack+fma fallback
#if __has_builtin(__builtin_amdgcn_fdot2_f32_bf16)
typedef __bf16 v2bf __attribute__((ext_vector_type(2)));
__device__ __forceinline__ float dot2u(uint32 w, uint32 v, float acc) {
    return __builtin_amdgcn_fdot2_f32_bf16(
        __builtin_bit_cast(v2bf, w), __builtin_bit_cast(v2bf, v), acc, false);
}
#else
__device__ __forceinline__ float dot2u(uint32 w, uint32 v, float acc) {
    acc = fmaf(lo2f(w), lo2f(v), acc);
    return fmaf(hi2f(w), hi2f(v), acc);
}
#endif
__device__ __forceinline__ float dot4(uint4 w, uint4 v, float acc) {
    acc = dot2u(w.x, v.x, acc); acc = dot2u(w.y, v.y, acc);
    acc = dot2u(w.z, v.z, acc); return dot2u(w.w, v.w, acc);
}

__global__ void cvt_f32_bf16(const float* __restrict__ src, ushort_t* __restrict__ dst, int n) {
    int i = blockIdx.x * 256 + threadIdx.x;
    if (i < n) dst[i] = f2b(src[i]);
}

// Swizzled fp32 -> bf16: uint4 index = ((row/64)*chunks + c)*64 + (row%64)
__global__ void cvt_swz(const float* __restrict__ src, ushort_t* __restrict__ dst,
                        int rows, int chunks) {
    int t = blockIdx.x * 256 + threadIdx.x;
    if (t >= rows * chunks) return;
    int row = t / chunks, c = t % chunks;
    const float* s = src + (size_t)row * chunks * 8 + c * 8;
    uint4 v;
    v.x = pack2(s[0], s[1]); v.y = pack2(s[2], s[3]);
    v.z = pack2(s[4], s[5]); v.w = pack2(s[6], s[7]);
    ((uint4*)dst)[((size_t)(row >> 6) * chunks + c) * 64 + (row & 63)] = v;
}

// One block (1024 threads) per batch row.
// Waves 0-11 ("gate"): thread tid owns row tid of Wih (reg-resident) + Whh
//   (4 chunks LDS-resident, 28 streamed from L2).
// Waves 12-15 ("attn"): (row 0..127) x (kslice 0..1) of Wa; 16/24 chunks in regs.
// 2 block barriers + 2 LDS flag syncs per step; Whh stream overlaps attention.
__global__ __launch_bounds__(1024, 4) void da_rnn_kernel(
    const float* __restrict__ x,          // fp32 [B,S,I]
    const ushort_t* __restrict__ wsb,     // bf16 blob in d_ws
    float* __restrict__ out)              // fp32 [B,1]
{
    const int b    = blockIdx.x;
    const int tid  = threadIdx.x;
    const int lane = tid & 63;
    const int wv   = tid >> 6;
    const bool is_gate = (tid < 3 * HH);

    __shared__ __align__(16) uint32 whh_lds[12288];  // 48 KB
    __shared__ __align__(16) uint32 s_xh_p[192];     // packed bf16 [x_t(128); h(256)]
    __shared__ __align__(16) uint32 sxw_p[64];       // packed bf16 alpha*x_t
    __shared__ __align__(16) float  sred[256];
    __shared__ __align__(16) float  sgi[3 * HH];     // input-side gate pre-acts
    __shared__ __align__(16) float  sgh[3 * HH];     // hidden-side gate pre-acts
    __shared__ __align__(16) float  sx[2][II];       // x_t fp32 double buffer
    __shared__ float swave[4];
    __shared__ int   flag_red;   // attn-wave arrival counter (monotonic)
    __shared__ int   flag_xw;    // sxw_p ready for step t (== t+1)

    if (tid == 0) { flag_red = 0; flag_xw = 0; }
    if (tid < II) s_xh_p[64 + tid] = 0u;             // h_0 = 0 (packed)

    // ---- role-overlaid register-resident weights (one 64-VGPR array) ----
    uint4 wreg[16];
    const int a   = tid - 3 * HH;                    // attn index 0..255
    const int row = a & 127;
    const int s   = a >> 7;
    const uint4* whh_base = (const uint4*)(wsb + OFF_WHH) + (size_t)wv * 32 * 64 + lane;
    const uint4* wa_st = nullptr;
    float bias_i = 0.f, bias_h = 0.f, ba_a = 0.f, ba_b = 0.f;

    if (is_gate) {
        const uint4* wih_g = (const uint4*)(wsb + OFF_WIH) + (size_t)wv * 16 * 64 + lane;
        #pragma unroll
        for (int c = 0; c < 16; ++c) wreg[c] = wih_g[c * 64];
        bias_i = b2f(wsb[OFF_BIH + tid]);
        bias_h = b2f(wsb[OFF_BHH + tid]);
        #pragma unroll
        for (int c = 0; c < 4; ++c)
            ((uint4*)whh_lds)[(wv * 4 + c) * 64 + lane] = whh_base[c * 64];
    } else {
        const uint4* wa_g = (const uint4*)(wsb + OFF_WA);
        const size_t gbase = ((size_t)(row >> 6) * 48 + s * 24) * 64 + (row & 63);
        #pragma unroll
        for (int i = 0; i < 16; ++i) wreg[i] = wa_g[gbase + (size_t)i * 64];
        wa_st = wa_g + gbase + (size_t)16 * 64;      // streamed chunks 16..23
        ba_a = b2f(wsb[OFF_BA + lane]);
        ba_b = b2f(wsb[OFF_BA + 64 + lane]);
    }

    float h_reg = 0.f, c_reg = 0.f, m_run = -2.0f, l_run = 0.f;
    float wt_j = 0.f, wf_j = 0.f, bt_r = 0.f;
    if (tid < HH) {
        wt_j = b2f(wsb[OFF_WT + tid]);
        wf_j = b2f(wsb[OFF_WF + tid]);
        bt_r = b2f(wsb[OFF_BT]);
    }

    const float* xrow = x + (size_t)b * SS * II;
    if (!is_gate && a >= 64 && a < 192) {            // x_0 load + pack
        const int idx = a - 64;
        float v = xrow[idx];
        sx[0][idx] = v;
        float vn = __shfl_down(v, 1);
        if (!(idx & 1)) s_xh_p[idx >> 1] = pack2(v, vn);
    }
    __syncthreads();

    const uint4* st4 = (const uint4*)s_xh_p;         // 48 chunks of [x;h]
    const uint4* shp = (const uint4*)s_xh_p + 16;    // 32 chunks of h
    const uint4* xwp = (const uint4*)sxw_p;          // 16 chunks of xw
    const uint4* whl = (const uint4*)whh_lds + (size_t)(wv * 4) * 64 + lane;

    for (int t = 0; t < SS; ++t) {
        const int p = t & 1;

        if (is_gate) {
            // gh = Whh . h_t : starts immediately, overlaps attention phase
            float gh = bias_h;
            #pragma unroll
            for (int c = 0; c < 4; ++c) gh = dot4(whl[c * 64], shp[c], gh);
            #pragma unroll 4
            for (int c = 4; c < 32; ++c) gh = dot4(whh_base[c * 64], shp[c], gh);
            sgh[tid] = gh;
            // wait for xw, then reg-resident Wih dot
            while (__hip_atomic_load(&flag_xw, __ATOMIC_ACQUIRE,
                                     __HIP_MEMORY_SCOPE_WORKGROUP) <= t) {}
            float gi = bias_i;
            #pragma unroll
            for (int c = 0; c < 16; ++c) gi = dot4(wreg[c], xwp[c], gi);
            sgi[tid] = gi;
        } else {
            // Wa partials: 16 reg chunks + 8 streamed chunks
            float acc = 0.f;
            #pragma unroll
            for (int i = 0; i < 16; ++i) acc = dot4(wreg[i], st4[s * 24 + i], acc);
            #pragma unroll 4
            for (int i = 0; i < 8; ++i) acc = dot4(wa_st[i * 64], st4[s * 24 + 16 + i], acc);
            sred[a] = acc;
            if (lane == 0)
                __hip_atomic_fetch_add(&flag_red, 1, __ATOMIC_ACQ_REL,
                                       __HIP_MEMORY_SCOPE_WORKGROUP);
            const int tgt = 4 * (t + 1);
            while (__hip_atomic_load(&flag_red, __ATOMIC_ACQUIRE,
                                     __HIP_MEMORY_SCOPE_WORKGROUP) < tgt) {}
            if (a < 64) {
                // wave 12: combine + tanh + softmax + packed xw
                float s_a = sred[lane] + sred[128 + lane] + ba_a;
                float s_b = sred[64 + lane] + sred[192 + lane] + ba_b;
                s_a = tanhf(s_a); s_b = tanhf(s_b);
                float m = fmaxf(s_a, s_b);
                for (int off = 32; off; off >>= 1) m = fmaxf(m, __shfl_xor(m, off));
                float e_a = expf(s_a - m), e_b = expf(s_b - m);
                float sum = e_a + e_b;
                for (int off = 32; off; off >>= 1) sum += __shfl_xor(sum, off);
                float inv = 1.f / sum;
                float xa = e_a * inv * sx[p][lane];
                float xb = e_b * inv * sx[p][64 + lane];
                float xa1 = __shfl_down(xa, 1), xb1 = __shfl_down(xb, 1);
                if (!(lane & 1)) {
                    sxw_p[lane >> 1]        = pack2(xa, xa1);
                    sxw_p[32 + (lane >> 1)] = pack2(xb, xb1);
                }
                if (lane == 0)
                    __hip_atomic_store(&flag_xw, t + 1, __ATOMIC_RELEASE,
                                       __HIP_MEMORY_SCOPE_WORKGROUP);
            } else if (a >= 64 && a < 192 && t + 1 < SS) {
                // waves 13-14: prefetch x_{t+1}
                const int idx = a - 64;
                float v = xrow[(t + 1) * II + idx];
                sx[p ^ 1][idx] = v;
                float vn = __shfl_down(v, 1);
                if (!(idx & 1)) s_xh_p[idx >> 1] = pack2(v, vn);
            }
        }
        __syncthreads();                              // B1: gates done, x prefetched

        if (tid < HH) {
            const float r = 1.f / (1.f + expf(-(sgi[tid] + sgh[tid])));
            const float z = 1.f / (1.f + expf(-(sgi[tid + HH] + sgh[tid + HH])));
            const float n = tanhf(sgi[tid + 2 * HH] + r * sgh[tid + 2 * HH]);
            h_reg = (1.f - z) * n + z * h_reg;
            float hn2 = __shfl_down(h_reg, 1);
            if (!(tid & 1)) s_xh_p[64 + (tid >> 1)] = pack2(h_reg, hn2);
            float pd = wt_j * h_reg;
            for (int off = 32; off; off >>= 1) pd += __shfl_down(pd, off);
            if (lane == 0) swave[wv] = pd;
        }
        __syncthreads();                              // B2: h ready (loop barrier)

        if (tid < HH) {
            // redundant per-thread online softmax over time (no extra barrier)
            float dot = swave[0] + swave[1] + swave[2] + swave[3] + bt_r;
            float st = tanhf(dot);
            float mn = fmaxf(m_run, st);
            float aa = expf(m_run - mn), ww = expf(st - mn);
            l_run = l_run * aa + ww;
            m_run = mn;
            c_reg = c_reg * aa + ww * h_reg;
        }
    }

    __syncthreads();
    if (tid < HH) {
        float ctx = c_reg / l_run;
        float pd = wf_j * ctx;
        for (int off = 32; off; off >>= 1) pd += __shfl_down(pd, off);
        if (lane == 0) swave[wv] = pd;
    }
    __syncthreads();
    if (tid == 0) {
        float logit = swave[0] + swave[1] + swave[2] + swave[3] + b2f(wsb[OFF_BF]);
        out[b] = 1.f / (1.f + expf(-logit));
    }
}

extern "C" void kernel_launch(void* const* d_in, const int* in_sizes, int n_in,
                              void* d_out, int out_size, void* d_ws, size_t ws_size,
                              hipStream_t stream) {
    ushort_t* wsb = (ushort_t*)d_ws;

    cvt_swz<<<dim3((128 * 48 + 255) / 256), dim3(256), 0, stream>>>(
        (const float*)d_in[1], wsb + OFF_WA, 128, 48);           // W_a  [128,384]
    cvt_swz<<<dim3((768 * 16 + 255) / 256), dim3(256), 0, stream>>>(
        (const float*)d_in[3], wsb + OFF_WIH, 768, 16);          // W_ih [768,128]
    cvt_swz<<<dim3((768 * 32 + 255) / 256), dim3(256), 0, stream>>>(
        (const float*)d_in[5], wsb + OFF_WHH, 768, 32);          // W_hh [768,256]

    struct { int src_idx; int off; int n; } cv[7] = {
        {2, OFF_BA,  II}, {4, OFF_BIH, 3 * HH}, {6, OFF_BHH, 3 * HH},
        {7, OFF_WT,  HH}, {8, OFF_BT, 1}, {9, OFF_WF, HH}, {10, OFF_BF, 1},
    };
    for (int i = 0; i < 7; ++i) {
        int blocks = (cv[i].n + 255) / 256;
        cvt_f32_bf16<<<dim3(blocks), dim3(256), 0, stream>>>(
            (const float*)d_in[cv[i].src_idx], wsb + cv[i].off, cv[i].n);
    }

    da_rnn_kernel<<<dim3(BB), dim3(1024), 0, stream>>>(
        (const float*)d_in[0], wsb, (float*)d_out);
}